// Round 4
// baseline (680.379 us; speedup 1.0000x reference)
//
#include <hip/hip_runtime.h>
#include <hip/hip_bf16.h>

// Bahdanau additive attention, MI355X. B=32, S=2048, E=D=1024. M = B*S = 65536.
// scores[m] = v . tanh(enc[m,:] @ w1 + qq[b]),  qq[b] = dec[b] @ w2 + b2 + b1
// (bv dropped: softmax-invariant). attn = softmax_s(scores); context[b] = attn[b,:] @ enc[b,:,:]
//
// BK=64 LDS image layout (per 128x64 bf16 tile = 16KB): row-major rows of
// 128B = 8 chunks of 16B; chunk c stored at position c ^ (row & 7).
// Conflict-free for ds_read_b128 fragment reads (each 8-lane phase hits 8
// distinct chunks) and for the fallback's ds_write_b128 staging.
// Both GEMM operands are pre-packed in global memory in this image order
// (enc via cvt_enc per launch, w1 via pack_w1) -> staging is pure
// global_load_lds width-16 DMA. BK=64 halves the per-iteration vmcnt(0)
// barrier drains (round-3 analysis: drain latency, not MFMA, was the bound).

typedef __attribute__((ext_vector_type(8))) short short8;   // 8 bf16 (4 VGPRs)
typedef __attribute__((ext_vector_type(4))) float f32x4;    // MFMA acc

#define M_TOTAL 65536
#define KDIM    1024

// pack two fp32 -> two bf16 (round-half-up) in one dword: 2 adds + 1 v_perm
static __device__ inline unsigned int pk2h(float a, float b) {
    unsigned int ua = __builtin_bit_cast(unsigned int, a) + 0x8000u;
    unsigned int ub = __builtin_bit_cast(unsigned int, b) + 0x8000u;
    return __builtin_amdgcn_perm(ub, ua, 0x07060302u);
}

static __device__ inline void async_copy16(const void* g, void* l) {
    __builtin_amdgcn_global_load_lds(
        (const __attribute__((address_space(1))) unsigned int*)g,
        (__attribute__((address_space(3))) unsigned int*)l, 16, 0, 0);
}

// ---- w1 [d][e] fp32 -> w1p bf16, BK=64 tiled+swizzled image order ----
// w1p[(nt*16+kc64)*8192 + r*64 + ((c)^(r&7))*8 + j], nt=e>>7, r=e&127,
// kc64=d>>6, c=(d>>3)&7, j=d&7
__global__ void pack_w1(const float* __restrict__ w1, unsigned short* __restrict__ w1p) {
    __shared__ float tile[32][33];
    const int tx = threadIdx.x, ty = threadIdx.y;
    tile[ty][tx] = w1[(blockIdx.y * 32 + ty) * 1024 + blockIdx.x * 32 + tx];
    __syncthreads();
    const int eo = blockIdx.x * 32 + ty;   // n-dim
    const int dq = blockIdx.y * 32 + tx;   // k-dim
    const unsigned int u = __builtin_bit_cast(unsigned int, tile[tx][ty]) + 0x8000u;
    const unsigned short us = (unsigned short)(u >> 16);
    const int nt = eo >> 7, r = eo & 127;
    const int kc = dq >> 6, c = (dq >> 3) & 7, j = dq & 7;
    const int cs = c ^ (r & 7);
    w1p[(((size_t)(nt * 16 + kc)) << 13) + (r << 6) + (cs << 3) + j] = us;
}

// ---- enc fp32 -> encp bf16, BK=64 image order. Linear 16B stores (1KB/instr
// per wave); the swizzle is applied on the LOAD side (inverse mapping). ----
// block g: mtile = g>>4 (512), kc64 = g&15
__global__ __launch_bounds__(256) void cvt_enc(const float* __restrict__ enc,
                                               unsigned short* __restrict__ encp) {
    const int g = blockIdx.x;
    const int kc = g & 15, mtile = g >> 4;
    const int tid = threadIdx.x;
    unsigned short* dstbase = encp + (((size_t)(mtile * 16 + kc)) << 13);
#pragma unroll
    for (int q = 0; q < 4; q++) {
        const int off = q * 2048 + tid * 8;      // linear elem offset in tile
        const int r = off >> 6;                  // = q*32 + (tid>>3)
        const int cp = tid & 7;                  // output chunk position
        const int csrc = cp ^ (r & 7);           // source chunk
        const float* src = enc + ((size_t)(mtile * 128 + r)) * 1024 + kc * 64 + csrc * 8;
        const float4 f0 = *reinterpret_cast<const float4*>(src);
        const float4 f1 = *reinterpret_cast<const float4*>(src + 4);
        uint4 w;
        w.x = pk2h(f0.x, f0.y); w.y = pk2h(f0.z, f0.w);
        w.z = pk2h(f1.x, f1.y); w.w = pk2h(f1.z, f1.w);
        *reinterpret_cast<uint4*>(dstbase + off) = w;
    }
}

// ---- qq[b][e] += partial of b1+b2 + dec[b]@w2, split-k x4 ----
__global__ __launch_bounds__(256) void qq_kern(const float* __restrict__ dec,
                                               const float* __restrict__ w2,
                                               const float* __restrict__ b1,
                                               const float* __restrict__ b2,
                                               float* __restrict__ qq) {
    const int b = blockIdx.y;
    const int e = blockIdx.x * 256 + threadIdx.x;
    const int d0 = blockIdx.z * 256;
    const float* db = dec + b * 1024;
    float acc = (blockIdx.z == 0) ? (b1[e] + b2[e]) : 0.f;
#pragma unroll 8
    for (int d = d0; d < d0 + 256; d++)
        acc = fmaf(db[d], w2[d * 1024 + e], acc);
    atomicAdd(&qq[b * 1024 + e], acc);
}

// ---- shared epilogue: tanh(C + qq)*v, quad butterfly, atomic into scores ----
static __device__ inline void score_epilogue(f32x4 acc[4][4], const float* qqb,
                                             const float* vvec, float* scores,
                                             int m0, int n0, int wm, int wn,
                                             int quad, int lc) {
    const int nb = n0 + wn * 64 + lc;
    float qn[4], vn[4];
#pragma unroll
    for (int ni = 0; ni < 4; ni++) {
        qn[ni] = qqb[nb + ni * 16];
        vn[ni] = vvec[nb + ni * 16];
    }
    float red[16];
#pragma unroll
    for (int mi = 0; mi < 4; mi++) {
#pragma unroll
        for (int r = 0; r < 4; r++) {
            float ssum = 0.f;
#pragma unroll
            for (int ni = 0; ni < 4; ni++) {
                float x = acc[mi][ni][r] + qn[ni];
                float e = __expf(2.0f * x);          // overflow-safe tanh
                float th = 1.0f - 2.0f / (e + 1.0f);
                ssum = fmaf(th, vn[ni], ssum);
            }
            float t = ssum;
            t += __shfl_xor(t, 1);
            t += __shfl_xor(t, 2);
            t += __shfl_xor(t, 4);
            t += __shfl_xor(t, 8);
            red[mi * 4 + r] = t;
        }
    }
    float myv = red[0];
#pragma unroll
    for (int i = 1; i < 16; i++)
        if (lc == i) myv = red[i];
    atomicAdd(scores + m0 + wm * 64 + (lc >> 2) * 16 + quad * 4 + (lc & 3), myv);
}

// ---- fused GEMM, BK=64, pure-DMA staging ----
__global__ __launch_bounds__(256) void score_gemm_dma(const unsigned short* __restrict__ encp,
                                                      const unsigned short* __restrict__ w1p,
                                                      const float* __restrict__ qq,
                                                      const float* __restrict__ vvec,
                                                      float* __restrict__ scores) {
    __shared__ __align__(16) unsigned short As[128 * 64];   // 16KB
    __shared__ __align__(16) unsigned short Bs[128 * 64];   // 16KB

    const int g = blockIdx.x;                   // 0..4095, XCD swizzle
    const int mtile = (g & 7) * 64 + (g >> 6);  // 0..511
    const int ntile = (g >> 3) & 7;             // 0..7
    const int m0 = mtile * 128;
    const int b = m0 >> 11;

    const int tid = threadIdx.x;
    const int wid = tid >> 6;
    const int lane = tid & 63;
    const int wm = wid >> 1, wn = wid & 1;
    const int quad = lane >> 4, lc = lane & 15;
    const int swz = lc & 7;                     // row&7 for rows i*16+lc
    const int fc0 = ((quad ^ swz) << 3);        // khalf 0 chunk offset (elems)
    const int fc1 = (((4 + quad) ^ swz) << 3);  // khalf 1

    f32x4 acc[4][4];
#pragma unroll
    for (int mi = 0; mi < 4; mi++)
#pragma unroll
        for (int ni = 0; ni < 4; ni++)
            acc[mi][ni] = (f32x4){0.f, 0.f, 0.f, 0.f};

    // per-wave: 2048 elems (4KB) of each 8192-elem tile, linear image copy
    const unsigned short* abase = encp + ((size_t)mtile << 17) + (wid << 11) + (lane << 3);
    const unsigned short* bbase = w1p + ((size_t)ntile << 17) + (wid << 11) + (lane << 3);
    unsigned short* adst = &As[wid << 11];
    unsigned short* bdst = &Bs[wid << 11];

    for (int k0 = 0; k0 < KDIM; k0 += 64) {
        __syncthreads();   // prior iteration's LDS reads done
        const size_t koff = (size_t)(k0 >> 6) << 13;
        const unsigned short* asrc = abase + koff;
        const unsigned short* bsrc = bbase + koff;
        async_copy16(asrc, adst);
        async_copy16(asrc + 512, adst + 512);
        async_copy16(asrc + 1024, adst + 1024);
        async_copy16(asrc + 1536, adst + 1536);
        async_copy16(bsrc, bdst);
        async_copy16(bsrc + 512, bdst + 512);
        async_copy16(bsrc + 1024, bdst + 1024);
        async_copy16(bsrc + 1536, bdst + 1536);
        __syncthreads();   // vmcnt(0): DMA complete

        short8 af[4], bf[4];
#pragma unroll
        for (int i = 0; i < 4; i++) {
            af[i] = *reinterpret_cast<const short8*>(&As[((wm * 64 + i * 16 + lc) << 6) + fc0]);
            bf[i] = *reinterpret_cast<const short8*>(&Bs[((wn * 64 + i * 16 + lc) << 6) + fc0]);
        }
#pragma unroll
        for (int mi = 0; mi < 4; mi++)
#pragma unroll
            for (int ni = 0; ni < 4; ni++)
                acc[mi][ni] = __builtin_amdgcn_mfma_f32_16x16x32_bf16(af[mi], bf[ni], acc[mi][ni], 0, 0, 0);
#pragma unroll
        for (int i = 0; i < 4; i++) {
            af[i] = *reinterpret_cast<const short8*>(&As[((wm * 64 + i * 16 + lc) << 6) + fc1]);
            bf[i] = *reinterpret_cast<const short8*>(&Bs[((wn * 64 + i * 16 + lc) << 6) + fc1]);
        }
#pragma unroll
        for (int mi = 0; mi < 4; mi++)
#pragma unroll
            for (int ni = 0; ni < 4; ni++)
                acc[mi][ni] = __builtin_amdgcn_mfma_f32_16x16x32_bf16(af[mi], bf[ni], acc[mi][ni], 0, 0, 0);
    }

    score_epilogue(acc, qq + b * 1024, vvec, scores, m0, ntile * 128, wm, wn, quad, lc);
}

// ---- fallback GEMM (ws too small): inline A convert, B DMA, BK=64 ----
__global__ __launch_bounds__(256) void score_gemm_fb(const float* __restrict__ enc,
                                                     const unsigned short* __restrict__ w1p,
                                                     const float* __restrict__ qq,
                                                     const float* __restrict__ vvec,
                                                     float* __restrict__ scores) {
    __shared__ __align__(16) unsigned short As[128 * 64];
    __shared__ __align__(16) unsigned short Bs[128 * 64];

    const int g = blockIdx.x;
    const int mtile = (g & 7) * 64 + (g >> 6);
    const int ntile = (g >> 3) & 7;
    const int m0 = mtile * 128;
    const int b = m0 >> 11;

    const int tid = threadIdx.x;
    const int wid = tid >> 6;
    const int lane = tid & 63;
    const int wm = wid >> 1, wn = wid & 1;
    const int quad = lane >> 4, lc = lane & 15;
    const int swz = lc & 7;
    const int fc0 = ((quad ^ swz) << 3);
    const int fc1 = (((4 + quad) ^ swz) << 3);

    const int sr = tid >> 1, sh = tid & 1;      // staging: row, half (32 elems)
    const int ssw = sr & 7;

    f32x4 acc[4][4];
#pragma unroll
    for (int mi = 0; mi < 4; mi++)
#pragma unroll
        for (int ni = 0; ni < 4; ni++)
            acc[mi][ni] = (f32x4){0.f, 0.f, 0.f, 0.f};

    const float* arow = enc + (size_t)(m0 + sr) * 1024 + sh * 32;
    const unsigned short* bbase = w1p + ((size_t)ntile << 17) + (wid << 11) + (lane << 3);
    unsigned short* bdst = &Bs[wid << 11];

    for (int k0 = 0; k0 < KDIM; k0 += 64) {
        float4 fv[8];
        const float4* a4 = reinterpret_cast<const float4*>(arow + k0);
#pragma unroll
        for (int j = 0; j < 8; j++) fv[j] = a4[j];
        __syncthreads();
        const unsigned short* bsrc = bbase + (((size_t)(k0 >> 6)) << 13);
        async_copy16(bsrc, bdst);
        async_copy16(bsrc + 512, bdst + 512);
        async_copy16(bsrc + 1024, bdst + 1024);
        async_copy16(bsrc + 1536, bdst + 1536);
#pragma unroll
        for (int q = 0; q < 4; q++) {
            uint4 w;
            w.x = pk2h(fv[2 * q].x, fv[2 * q].y);     w.y = pk2h(fv[2 * q].z, fv[2 * q].w);
            w.z = pk2h(fv[2 * q + 1].x, fv[2 * q + 1].y); w.w = pk2h(fv[2 * q + 1].z, fv[2 * q + 1].w);
            *reinterpret_cast<uint4*>(&As[(sr << 6) + (((sh * 4 + q) ^ ssw) << 3)]) = w;
        }
        __syncthreads();

        short8 af[4], bf[4];
#pragma unroll
        for (int i = 0; i < 4; i++) {
            af[i] = *reinterpret_cast<const short8*>(&As[((wm * 64 + i * 16 + lc) << 6) + fc0]);
            bf[i] = *reinterpret_cast<const short8*>(&Bs[((wn * 64 + i * 16 + lc) << 6) + fc0]);
        }
#pragma unroll
        for (int mi = 0; mi < 4; mi++)
#pragma unroll
            for (int ni = 0; ni < 4; ni++)
                acc[mi][ni] = __builtin_amdgcn_mfma_f32_16x16x32_bf16(af[mi], bf[ni], acc[mi][ni], 0, 0, 0);
#pragma unroll
        for (int i = 0; i < 4; i++) {
            af[i] = *reinterpret_cast<const short8*>(&As[((wm * 64 + i * 16 + lc) << 6) + fc1]);
            bf[i] = *reinterpret_cast<const short8*>(&Bs[((wn * 64 + i * 16 + lc) << 6) + fc1]);
        }
#pragma unroll
        for (int mi = 0; mi < 4; mi++)
#pragma unroll
            for (int ni = 0; ni < 4; ni++)
                acc[mi][ni] = __builtin_amdgcn_mfma_f32_16x16x32_bf16(af[mi], bf[ni], acc[mi][ni], 0, 0, 0);
    }

    score_epilogue(acc, qq + b * 1024, vvec, scores, m0, ntile * 128, wm, wn, quad, lc);
}

// ---- softmax over s (2048) per batch ----
__global__ __launch_bounds__(256) void softmax_kern(const float* __restrict__ scores,
                                                    float* __restrict__ attn) {
    const int b = blockIdx.x;
    const int tid = threadIdx.x;
    const int wid = tid >> 6, lane = tid & 63;
    const float* s = scores + b * 2048;
    float x[8];
    float m = -1e30f;
#pragma unroll
    for (int i = 0; i < 8; i++) {
        x[i] = s[tid + i * 256];
        m = fmaxf(m, x[i]);
    }
    for (int off = 1; off < 64; off <<= 1) m = fmaxf(m, __shfl_xor(m, off));
    __shared__ float redm[4];
    if (lane == 0) redm[wid] = m;
    __syncthreads();
    m = fmaxf(fmaxf(redm[0], redm[1]), fmaxf(redm[2], redm[3]));
    float sum = 0.f;
#pragma unroll
    for (int i = 0; i < 8; i++) {
        x[i] = __expf(x[i] - m);
        sum += x[i];
    }
    for (int off = 1; off < 64; off <<= 1) sum += __shfl_xor(sum, off);
    __shared__ float reds[4];
    if (lane == 0) reds[wid] = sum;
    __syncthreads();
    sum = reds[0] + reds[1] + reds[2] + reds[3];
    const float inv = 1.0f / sum;
#pragma unroll
    for (int i = 0; i < 8; i++) attn[b * 2048 + tid + i * 256] = x[i] * inv;
}

// ---- context from bf16 encp image: halves ctx HBM traffic ----
__global__ __launch_bounds__(256) void ctx_kern_bf(const float* __restrict__ attn,
                                                   const unsigned short* __restrict__ encp,
                                                   float* __restrict__ out) {
    const int b = blockIdx.y, sc = blockIdx.x;   // 32 x (32 chunks of 64 s)
    const int tid = threadIdx.x;
    const int o = tid & 127, h = tid >> 7;       // e-octet, row-parity
    const int m0 = b * 2048 + sc * 64;
    const int mtile = m0 >> 7;
    const int rbase = m0 & 127;                  // 0 or 64
    const unsigned short* tbase = encp + (((size_t)(mtile * 16 + (o >> 3))) << 13);
    const int co = o & 7;
    const float* ab = attn + b * 2048 + sc * 64;
    float a8[8] = {0.f, 0.f, 0.f, 0.f, 0.f, 0.f, 0.f, 0.f};
#pragma unroll 8
    for (int si = h; si < 64; si += 2) {
        const int r = rbase + si;
        const float w = ab[si];
        const uint4 u = *reinterpret_cast<const uint4*>(tbase + (r << 6) + ((co ^ (r & 7)) << 3));
        const unsigned int uu[4] = {u.x, u.y, u.z, u.w};
#pragma unroll
        for (int p = 0; p < 4; p++) {
            const float lo = __builtin_bit_cast(float, uu[p] << 16);
            const float hi = __builtin_bit_cast(float, uu[p] & 0xffff0000u);
            a8[p * 2]     = fmaf(w, lo, a8[p * 2]);
            a8[p * 2 + 1] = fmaf(w, hi, a8[p * 2 + 1]);
        }
    }
    float* op = out + b * 1024 + o * 8;
#pragma unroll
    for (int p = 0; p < 8; p++) atomicAdd(op + p, a8[p]);
}

// ---- fp32 context (fallback path only) ----
__global__ __launch_bounds__(256) void ctx_kern_f32(const float* __restrict__ attn,
                                                    const float* __restrict__ enc,
                                                    float* __restrict__ out) {
    const int b = blockIdx.y;
    const int sc = blockIdx.x;
    const int tid = threadIdx.x;
    const float* ab = attn + b * 2048 + sc * 64;
    const float* eb = enc + ((size_t)b * 2048 + sc * 64) * 1024 + tid * 4;
    float4 acc = {0.f, 0.f, 0.f, 0.f};
#pragma unroll 16
    for (int s = 0; s < 64; s++) {
        float w = ab[s];
        float4 ev = *reinterpret_cast<const float4*>(eb + (size_t)s * 1024);
        acc.x = fmaf(w, ev.x, acc.x);
        acc.y = fmaf(w, ev.y, acc.y);
        acc.z = fmaf(w, ev.z, acc.z);
        acc.w = fmaf(w, ev.w, acc.w);
    }
    float* op = out + b * 1024 + tid * 4;
    atomicAdd(op + 0, acc.x);
    atomicAdd(op + 1, acc.y);
    atomicAdd(op + 2, acc.z);
    atomicAdd(op + 3, acc.w);
}

extern "C" void kernel_launch(void* const* d_in, const int* in_sizes, int n_in,
                              void* d_out, int out_size, void* d_ws, size_t ws_size,
                              hipStream_t stream) {
    const float* enc = (const float*)d_in[0];  // 32*2048*1024
    const float* dec = (const float*)d_in[1];  // 32*1*1024
    const float* w1  = (const float*)d_in[2];  // 1024*1024
    const float* b1  = (const float*)d_in[3];  // 1024
    const float* w2  = (const float*)d_in[4];  // 1024*1024
    const float* b2  = (const float*)d_in[5];  // 1024
    const float* v   = (const float*)d_in[6];  // 1024
    // d_in[7] = bv, softmax-invariant, unused
    float* out = (float*)d_out;                // 32*1024

    char* ws = (char*)d_ws;
    unsigned short* w1p = (unsigned short*)ws;                 // 2 MB
    float* qq     = (float*)(ws + (2u << 20));                 // 128 KB
    float* scores = (float*)(ws + (2u << 20) + (128u << 10));  // 256 KB
    float* attn   = scores + M_TOTAL;                          // 256 KB
    unsigned short* encp = (unsigned short*)(ws + (4u << 20)); // 128 MB

    const size_t need = (4ull << 20) + ((size_t)M_TOTAL * KDIM * 2);
    const bool big = ws_size >= need;

    hipMemsetAsync(qq, 0, (128u << 10) + M_TOTAL * sizeof(float), stream);
    hipMemsetAsync(out, 0, 32 * 1024 * sizeof(float), stream);

    pack_w1<<<dim3(32, 32), dim3(32, 32), 0, stream>>>(w1, w1p);
    qq_kern<<<dim3(4, 32, 4), 256, 0, stream>>>(dec, w2, b1, b2, qq);
    if (big) {
        cvt_enc<<<8192, 256, 0, stream>>>(enc, encp);
        score_gemm_dma<<<4096, 256, 0, stream>>>(encp, w1p, qq, v, scores);
        softmax_kern<<<32, 256, 0, stream>>>(scores, attn);
        ctx_kern_bf<<<dim3(32, 32), 256, 0, stream>>>(attn, encp, out);
    } else {
        score_gemm_fb<<<4096, 256, 0, stream>>>(enc, w1p, qq, v, scores);
        softmax_kern<<<32, 256, 0, stream>>>(scores, attn);
        ctx_kern_f32<<<dim3(32, 32), 256, 0, stream>>>(attn, enc, out);
    }
}

// Round 5
// 651.719 us; speedup vs baseline: 1.0440x; 1.0440x over previous
//
#include <hip/hip_runtime.h>
#include <hip/hip_bf16.h>

// Bahdanau additive attention, MI355X. B=32, S=2048, E=D=1024. M = B*S = 65536.
// scores[m] = v . tanh(enc[m,:] @ w1 + qq[b]),  qq[b] = dec[b] @ w2 + b2 + b1
// (bv dropped: softmax-invariant). attn = softmax_s(scores); context[b] = attn[b,:] @ enc[b,:,:]
//
// Round-5 structure: NO encp pre-pass (round-4 showed the cvt pipeline +
// 132MB workspace cost more than it saved). The GEMM converts A inline:
//   barrier1 -> issue B-DMA (async) + A fp32 loads -> convert/ds_write
//   -> barrier2 (single latency window) -> ds_read frags -> MFMA.
// BK=64 LDS image (per 128x64 bf16 tile): rows of 128B = 8 chunks of 16B,
// logical chunk c stored at position c ^ (row & 7). Conflict-free for
// ds_write_b128 staging (each 8-lane phase = one row's 8 chunks = 32 banks)
// and ds_read_b128 fragment reads (verified: rounds 2-4 SQ_LDS_BANK_CONFLICT=0).
// w1 remains pre-packed in this image order -> B stages via pure
// global_load_lds width-16 DMA.

typedef __attribute__((ext_vector_type(8))) short short8;   // 8 bf16 (4 VGPRs)
typedef __attribute__((ext_vector_type(4))) float f32x4;    // MFMA acc

#define M_TOTAL 65536
#define KDIM    1024

// pack two fp32 -> two bf16 (round-half-up) in one dword: 2 adds + 1 v_perm
static __device__ inline unsigned int pk2h(float a, float b) {
    unsigned int ua = __builtin_bit_cast(unsigned int, a) + 0x8000u;
    unsigned int ub = __builtin_bit_cast(unsigned int, b) + 0x8000u;
    return __builtin_amdgcn_perm(ub, ua, 0x07060302u);
}

static __device__ inline void async_copy16(const void* g, void* l) {
    __builtin_amdgcn_global_load_lds(
        (const __attribute__((address_space(1))) unsigned int*)g,
        (__attribute__((address_space(3))) unsigned int*)l, 16, 0, 0);
}

// ---- w1 [d][e] fp32 -> w1p bf16, BK=64 tiled+swizzled image order ----
// w1p[(nt*16+kc64)*8192 + r*64 + ((c)^(r&7))*8 + j], nt=e>>7, r=e&127,
// kc64=d>>6, c=(d>>3)&7, j=d&7
__global__ void pack_w1(const float* __restrict__ w1, unsigned short* __restrict__ w1p) {
    __shared__ float tile[32][33];
    const int tx = threadIdx.x, ty = threadIdx.y;
    tile[ty][tx] = w1[(blockIdx.y * 32 + ty) * 1024 + blockIdx.x * 32 + tx];
    __syncthreads();
    const int eo = blockIdx.x * 32 + ty;   // n-dim
    const int dq = blockIdx.y * 32 + tx;   // k-dim
    const unsigned int u = __builtin_bit_cast(unsigned int, tile[tx][ty]) + 0x8000u;
    const unsigned short us = (unsigned short)(u >> 16);
    const int nt = eo >> 7, r = eo & 127;
    const int kc = dq >> 6, c = (dq >> 3) & 7, j = dq & 7;
    const int cs = c ^ (r & 7);
    w1p[(((size_t)(nt * 16 + kc)) << 13) + (r << 6) + (cs << 3) + j] = us;
}

// ---- qq[b][e] += partial of b1+b2 + dec[b]@w2, split-k x4 ----
__global__ __launch_bounds__(256) void qq_kern(const float* __restrict__ dec,
                                               const float* __restrict__ w2,
                                               const float* __restrict__ b1,
                                               const float* __restrict__ b2,
                                               float* __restrict__ qq) {
    const int b = blockIdx.y;
    const int e = blockIdx.x * 256 + threadIdx.x;
    const int d0 = blockIdx.z * 256;
    const float* db = dec + b * 1024;
    float acc = (blockIdx.z == 0) ? (b1[e] + b2[e]) : 0.f;
#pragma unroll 8
    for (int d = d0; d < d0 + 256; d++)
        acc = fmaf(db[d], w2[d * 1024 + e], acc);
    atomicAdd(&qq[b * 1024 + e], acc);
}

// ---- epilogue: tanh(C + qq)*v, quad butterfly, atomic into scores ----
static __device__ inline void score_epilogue(f32x4 acc[4][4], const float* qqb,
                                             const float* vvec, float* scores,
                                             int m0, int n0, int wm, int wn,
                                             int quad, int lc) {
    const int nb = n0 + wn * 64 + lc;
    float qn[4], vn[4];
#pragma unroll
    for (int ni = 0; ni < 4; ni++) {
        qn[ni] = qqb[nb + ni * 16];
        vn[ni] = vvec[nb + ni * 16];
    }
    float red[16];
#pragma unroll
    for (int mi = 0; mi < 4; mi++) {
#pragma unroll
        for (int r = 0; r < 4; r++) {
            float ssum = 0.f;
#pragma unroll
            for (int ni = 0; ni < 4; ni++) {
                float x = acc[mi][ni][r] + qn[ni];
                float e = __expf(2.0f * x);          // overflow-safe tanh
                float th = 1.0f - 2.0f / (e + 1.0f);
                ssum = fmaf(th, vn[ni], ssum);
            }
            float t = ssum;
            t += __shfl_xor(t, 1);
            t += __shfl_xor(t, 2);
            t += __shfl_xor(t, 4);
            t += __shfl_xor(t, 8);
            red[mi * 4 + r] = t;
        }
    }
    float myv = red[0];
#pragma unroll
    for (int i = 1; i < 16; i++)
        if (lc == i) myv = red[i];
    atomicAdd(scores + m0 + wm * 64 + (lc >> 2) * 16 + quad * 4 + (lc & 3), myv);
}

// ---- fused GEMM, BK=64: inline A convert (single latency window), B DMA ----
__global__ __launch_bounds__(256) void score_gemm(const float* __restrict__ enc,
                                                  const unsigned short* __restrict__ w1p,
                                                  const float* __restrict__ qq,
                                                  const float* __restrict__ vvec,
                                                  float* __restrict__ scores) {
    __shared__ __align__(16) unsigned short As[128 * 64];   // 16KB
    __shared__ __align__(16) unsigned short Bs[128 * 64];   // 16KB

    const int g = blockIdx.x;                   // 0..4095, XCD swizzle:
    const int mtile = (g & 7) * 64 + (g >> 6);  // 8 n-tiles of an m-strip
    const int ntile = (g >> 3) & 7;             // land on one XCD
    const int m0 = mtile * 128;
    const int b = m0 >> 11;

    const int tid = threadIdx.x;
    const int wid = tid >> 6;
    const int lane = tid & 63;
    const int wm = wid >> 1, wn = wid & 1;
    const int quad = lane >> 4, lc = lane & 15;
    const int swz = lc & 7;                     // row&7 for rows i*16+lc
    const int fc0 = ((quad ^ swz) << 3);        // khalf 0 chunk offset (elems)
    const int fc1 = (((4 + quad) ^ swz) << 3);  // khalf 1

    // A staging: j=0..3, row r = (tid>>3) + 32*j, cols c*8..c*8+7 (c=tid&7).
    // Per 8 lanes: one full 256B row-segment (coalesced). Store at chunk c^(r&7).
    const int sr0 = tid >> 3;                   // base row
    const int sc = tid & 7;                     // logical chunk

    f32x4 acc[4][4];
#pragma unroll
    for (int mi = 0; mi < 4; mi++)
#pragma unroll
        for (int ni = 0; ni < 4; ni++)
            acc[mi][ni] = (f32x4){0.f, 0.f, 0.f, 0.f};

    const unsigned short* bbase = w1p + ((size_t)ntile << 17) + (wid << 11) + (lane << 3);
    unsigned short* bdst = &Bs[wid << 11];

    for (int k0 = 0; k0 < KDIM; k0 += 64) {
        __syncthreads();   // barrier1: prior iteration's LDS reads done

        // B: pure DMA (w1p pre-packed in LDS-image order)
        const unsigned short* bsrc = bbase + (((size_t)(k0 >> 6)) << 13);
        async_copy16(bsrc, bdst);
        async_copy16(bsrc + 512, bdst + 512);
        async_copy16(bsrc + 1024, bdst + 1024);
        async_copy16(bsrc + 1536, bdst + 1536);

        // A: fp32 loads issued here -> latency overlaps the B-DMA window
        float4 fv[8];
#pragma unroll
        for (int j = 0; j < 4; j++) {
            const float* src = enc + (size_t)(m0 + sr0 + 32 * j) * 1024 + k0 + sc * 8;
            fv[2 * j]     = *reinterpret_cast<const float4*>(src);
            fv[2 * j + 1] = *reinterpret_cast<const float4*>(src + 4);
        }
#pragma unroll
        for (int j = 0; j < 4; j++) {
            const int r = sr0 + 32 * j;
            uint4 w;
            w.x = pk2h(fv[2 * j].x, fv[2 * j].y);
            w.y = pk2h(fv[2 * j].z, fv[2 * j].w);
            w.z = pk2h(fv[2 * j + 1].x, fv[2 * j + 1].y);
            w.w = pk2h(fv[2 * j + 1].z, fv[2 * j + 1].w);
            *reinterpret_cast<uint4*>(&As[(r << 6) + ((sc ^ (r & 7)) << 3)]) = w;
        }

        __syncthreads();   // barrier2: drains B-DMA + A ds_writes (one window)

        short8 af[4], bf[4];
#pragma unroll
        for (int i = 0; i < 4; i++) {
            af[i] = *reinterpret_cast<const short8*>(&As[((wm * 64 + i * 16 + lc) << 6) + fc0]);
            bf[i] = *reinterpret_cast<const short8*>(&Bs[((wn * 64 + i * 16 + lc) << 6) + fc0]);
        }
#pragma unroll
        for (int mi = 0; mi < 4; mi++)
#pragma unroll
            for (int ni = 0; ni < 4; ni++)
                acc[mi][ni] = __builtin_amdgcn_mfma_f32_16x16x32_bf16(af[mi], bf[ni], acc[mi][ni], 0, 0, 0);
#pragma unroll
        for (int i = 0; i < 4; i++) {
            af[i] = *reinterpret_cast<const short8*>(&As[((wm * 64 + i * 16 + lc) << 6) + fc1]);
            bf[i] = *reinterpret_cast<const short8*>(&Bs[((wn * 64 + i * 16 + lc) << 6) + fc1]);
        }
#pragma unroll
        for (int mi = 0; mi < 4; mi++)
#pragma unroll
            for (int ni = 0; ni < 4; ni++)
                acc[mi][ni] = __builtin_amdgcn_mfma_f32_16x16x32_bf16(af[mi], bf[ni], acc[mi][ni], 0, 0, 0);
    }

    score_epilogue(acc, qq + b * 1024, vvec, scores, m0, ntile * 128, wm, wn, quad, lc);
}

// ---- softmax over s (2048) per batch ----
__global__ __launch_bounds__(256) void softmax_kern(const float* __restrict__ scores,
                                                    float* __restrict__ attn) {
    const int b = blockIdx.x;
    const int tid = threadIdx.x;
    const int wid = tid >> 6, lane = tid & 63;
    const float* s = scores + b * 2048;
    float x[8];
    float m = -1e30f;
#pragma unroll
    for (int i = 0; i < 8; i++) {
        x[i] = s[tid + i * 256];
        m = fmaxf(m, x[i]);
    }
    for (int off = 1; off < 64; off <<= 1) m = fmaxf(m, __shfl_xor(m, off));
    __shared__ float redm[4];
    if (lane == 0) redm[wid] = m;
    __syncthreads();
    m = fmaxf(fmaxf(redm[0], redm[1]), fmaxf(redm[2], redm[3]));
    float sum = 0.f;
#pragma unroll
    for (int i = 0; i < 8; i++) {
        x[i] = __expf(x[i] - m);
        sum += x[i];
    }
    for (int off = 1; off < 64; off <<= 1) sum += __shfl_xor(sum, off);
    __shared__ float reds[4];
    if (lane == 0) reds[wid] = sum;
    __syncthreads();
    sum = reds[0] + reds[1] + reds[2] + reds[3];
    const float inv = 1.0f / sum;
#pragma unroll
    for (int i = 0; i < 8; i++) attn[b * 2048 + tid + i * 256] = x[i] * inv;
}

// ---- context[b][e] = sum_s attn[b][s] * enc[b][s][e] ----
__global__ __launch_bounds__(256) void ctx_kern(const float* __restrict__ attn,
                                                const float* __restrict__ enc,
                                                float* __restrict__ out) {
    const int b = blockIdx.y;
    const int sc = blockIdx.x;    // 32 chunks x 64 s
    const int tid = threadIdx.x;
    const float* ab = attn + b * 2048 + sc * 64;
    const float* eb = enc + ((size_t)b * 2048 + sc * 64) * 1024 + tid * 4;
    float4 acc = {0.f, 0.f, 0.f, 0.f};
#pragma unroll 16
    for (int s = 0; s < 64; s++) {
        float w = ab[s];
        float4 ev = *reinterpret_cast<const float4*>(eb + (size_t)s * 1024);
        acc.x = fmaf(w, ev.x, acc.x);
        acc.y = fmaf(w, ev.y, acc.y);
        acc.z = fmaf(w, ev.z, acc.z);
        acc.w = fmaf(w, ev.w, acc.w);
    }
    float* op = out + b * 1024 + tid * 4;
    atomicAdd(op + 0, acc.x);
    atomicAdd(op + 1, acc.y);
    atomicAdd(op + 2, acc.z);
    atomicAdd(op + 3, acc.w);
}

extern "C" void kernel_launch(void* const* d_in, const int* in_sizes, int n_in,
                              void* d_out, int out_size, void* d_ws, size_t ws_size,
                              hipStream_t stream) {
    const float* enc = (const float*)d_in[0];  // 32*2048*1024
    const float* dec = (const float*)d_in[1];  // 32*1*1024
    const float* w1  = (const float*)d_in[2];  // 1024*1024
    const float* b1  = (const float*)d_in[3];  // 1024
    const float* w2  = (const float*)d_in[4];  // 1024*1024
    const float* b2  = (const float*)d_in[5];  // 1024
    const float* v   = (const float*)d_in[6];  // 1024
    // d_in[7] = bv, softmax-invariant, unused
    float* out = (float*)d_out;                // 32*1024

    char* ws = (char*)d_ws;
    unsigned short* w1p = (unsigned short*)ws;                 // 2 MB
    float* qq     = (float*)(ws + (2u << 20));                 // 128 KB
    float* scores = (float*)(ws + (2u << 20) + (128u << 10));  // 256 KB
    float* attn   = scores + M_TOTAL;                          // 256 KB
    // total ws need: ~2.65 MB (small footprint keeps enc warm in L3)

    hipMemsetAsync(qq, 0, (128u << 10) + M_TOTAL * sizeof(float), stream);
    hipMemsetAsync(out, 0, 32 * 1024 * sizeof(float), stream);

    pack_w1<<<dim3(32, 32), dim3(32, 32), 0, stream>>>(w1, w1p);
    qq_kern<<<dim3(4, 32, 4), 256, 0, stream>>>(dec, w2, b1, b2, qq);
    score_gemm<<<4096, 256, 0, stream>>>(enc, w1p, qq, v, scores);
    softmax_kern<<<32, 256, 0, stream>>>(scores, attn);
    ctx_kern<<<dim3(32, 32), 256, 0, stream>>>(attn, enc, out);
}